// Round 20
// baseline (216.762 us; speedup 1.0000x reference)
//
#include <hip/hip_runtime.h>

#define DEV __device__ __forceinline__

typedef __attribute__((ext_vector_type(8))) short s8v;
typedef __attribute__((ext_vector_type(4))) short s4v;
typedef __attribute__((ext_vector_type(4))) float f4v;

DEV unsigned short f2b(float f){
    unsigned u = __float_as_uint(f);
    u = (u + 0x7FFFu + ((u >> 16) & 1u)) >> 16;
    return (unsigned short)u;
}
DEV float b2f(short s){ return __uint_as_float(((unsigned)(unsigned short)s) << 16); }

DEV unsigned cvtpk(float lo, float hi){
    unsigned r;
    asm("v_cvt_pk_bf16_f32 %0, %1, %2" : "=v"(r) : "v"(lo), "v"(hi));
    return r;
}
DEV float exp2v(float x){
    float r;
    asm("v_exp_f32 %0, %1" : "=v"(r) : "v"(x));
    return r;
}

DEV void gload16(const void* g, void* l){
    __builtin_amdgcn_global_load_lds(
        (const __attribute__((address_space(1))) unsigned*)g,
        (__attribute__((address_space(3))) unsigned*)l, 16, 0, 0);
}

// B=4, S=1024, D=1024, H=8, E=4, K=2, DH=128

// ---- shared GEMM pieces: 128x128 tile, BK=64, XOR-swizzled LDS (used by gemmo) ----
DEV void stage2(const short* A, const short* B, int sA, int sB, int kA, int kB,
                short* la, short* lb, int w, int lane){
    int srow = lane >> 3;
    int swcol = ((lane & 7) ^ srow) << 3;
    #pragma unroll
    for(int it = 0; it < 4; it++){
        int seg = (w << 2) + it;
        int row = (seg << 3) + srow;
        gload16(&A[(size_t)row * sA + kA + swcol], &la[seg << 9]);
        gload16(&B[(size_t)row * sB + kB + swcol], &lb[seg << 9]);
    }
}

DEV void mfma_block(const short* la, const short* lb, int wm, int wn, int qr, int grp, f4v acc[4][4]){
    #pragma unroll
    for(int ks = 0; ks < 2; ks++){
        s8v af[4], bf[4];
        #pragma unroll
        for(int m = 0; m < 4; m++)
            af[m] = *(const s8v*)&la[(wm + m * 16 + qr) * 64 + ((((ks << 2) + grp) ^ (qr & 7)) << 3)];
        #pragma unroll
        for(int n = 0; n < 4; n++)
            bf[n] = *(const s8v*)&lb[(wn + n * 16 + qr) * 64 + ((((ks << 2) + grp) ^ (qr & 7)) << 3)];
        #pragma unroll
        for(int m = 0; m < 4; m++)
            #pragma unroll
            for(int n = 0; n < 4; n++)
                acc[m][n] = __builtin_amdgcn_mfma_f32_16x16x32_bf16(af[m], bf[n], acc[m][n], 0, 0, 0);
    }
}

// ---------------- prep mega-kernel: cvt (7168) + transposeWv (4096) + transposeWo (4096)
// + rlogits (512), flat block-id dispatch, grid 15872; block 0 also zeroes cntv
__global__ __launch_bounds__(256) void k_prep(const float* q_src, const float* k_src, const float* v_src,
                                              const float* Wq, const float* Wk, const float* Wv,
                                              const float* Wo, const float* selv, const float* selo,
                                              short* qsb, short* ksb, short* vsb, short* wqb, short* wkb,
                                              short* wvt, short* wot, float* part, int* cntv){
    __shared__ __align__(16) char smem[23040];
    int bid = blockIdx.x, tid = threadIdx.x;
    if(bid == 0 && tid < 32) cntv[tid] = 0;   // cntv consumed only by k_rfinal (after prep)
    if(bid < 7168){
        // ---- fp32 -> bf16 bulk convert
        int y, idx;
        if(bid < 6144){ y = bid >> 11; idx = (bid & 2047) * 256 + tid; }
        else { int i = bid - 6144; y = 3 + (i >> 9); idx = (i & 511) * 256 + tid; }
        const float* s = (y == 0) ? q_src : (y == 1) ? k_src : (y == 2) ? v_src : (y == 3) ? Wq : Wk;
        short* o = (y == 0) ? qsb : (y == 1) ? ksb : (y == 2) ? vsb : (y == 3) ? wqb : wkb;
        const float4* f = (const float4*)(s + (size_t)idx * 8);
        float4 a = f[0], b = f[1];
        s8v v;
        v[0] = f2b(a.x); v[1] = f2b(a.y); v[2] = f2b(a.z); v[3] = f2b(a.w);
        v[4] = f2b(b.x); v[5] = f2b(b.y); v[6] = f2b(b.z); v[7] = f2b(b.w);
        *(s8v*)(o + (size_t)idx * 8) = v;
    } else if(bid < 15360){
        // ---- transpose fp32 -> bf16
        const float* in; short* out; int R, C, c0, r0;
        if(bid < 11264){
            int i = bid - 7168;
            int z = i >> 7, rem = i & 127;
            R = 1024; C = 128;
            c0 = (rem & 3) * 32; r0 = (rem >> 2) * 32;
            in = Wv + (size_t)z * 131072;
            out = wvt + (size_t)z * 131072;
        } else {
            int i = bid - 11264;
            R = 4096; C = 1024;
            c0 = (i & 31) * 32; r0 = (i >> 5) * 32;
            in = Wo; out = wot;
        }
        float (*t)[33] = (float(*)[33])smem;
        int tx = tid & 31, ty = tid >> 5;
        #pragma unroll
        for(int p = 0; p < 4; p++){
            int r = p * 8 + ty;
            t[r][tx] = in[(size_t)(r0 + r) * C + c0 + tx];
        }
        __syncthreads();
        #pragma unroll
        for(int p = 0; p < 4; p++){
            int c = p * 8 + ty;
            out[(size_t)(c0 + c) * R + r0 + tx] = (short)f2b(t[tx][c]);
        }
    } else {
        // ---- routing logits: register-blocked fp32 GEMM, K-split x8
        int i = bid - 15360;
        int which = i & 1, bx = i >> 1;
        const float* src = which ? q_src : k_src;
        const float* sel = which ? selo : selv;
        int tt = bx >> 3, ks = bx & 7;
        int tok0 = tt << 7;
        float* lsrc = (float*)smem;              // [128][36]
        float* lsel = (float*)(smem + 18432);    // [32][36]
        int ts = tid & 31, es = tid >> 5;
        float acc[4][4];
        #pragma unroll
        for(int j = 0; j < 4; j++)
            #pragma unroll
            for(int q = 0; q < 4; q++) acc[j][q] = 0.f;
        #pragma unroll 1
        for(int c = 0; c < 4; c++){
            int k0 = (ks << 7) + (c << 5);
            {
                int row = tid >> 1, half = tid & 1;
                const float4* g = (const float4*)(src + (size_t)(tok0 + row) * 1024 + k0 + half * 16);
                #pragma unroll
                for(int qq = 0; qq < 4; qq++){
                    int qw = half * 4 + qq;
                    *(float4*)&lsrc[row * 36 + ((qw + row) & 7) * 4] = g[qq];
                }
            }
            {
                int row = tid >> 3, qw = tid & 7;
                *(float4*)&lsel[row * 36 + ((qw + row) & 7) * 4] =
                    *(const float4*)(sel + (size_t)row * 1024 + k0 + qw * 4);
            }
            __syncthreads();
            #pragma unroll
            for(int q = 0; q < 8; q++){
                float4 sv[4];
                #pragma unroll
                for(int v = 0; v < 4; v++){
                    int e = es * 4 + v;
                    sv[v] = *(const float4*)&lsel[e * 36 + ((q + e) & 7) * 4];
                }
                int slot = ((q + ts) & 7) * 4;
                #pragma unroll
                for(int j = 0; j < 4; j++){
                    float4 xv = *(const float4*)&lsrc[(ts + 32 * j) * 36 + slot];
                    #pragma unroll
                    for(int v = 0; v < 4; v++){
                        acc[j][v] = fmaf(xv.x, sv[v].x, acc[j][v]);
                        acc[j][v] = fmaf(xv.y, sv[v].y, acc[j][v]);
                        acc[j][v] = fmaf(xv.z, sv[v].z, acc[j][v]);
                        acc[j][v] = fmaf(xv.w, sv[v].w, acc[j][v]);
                    }
                }
            }
            __syncthreads();
        }
        #pragma unroll
        for(int j = 0; j < 4; j++){
            int token = tok0 + ts + 32 * j;
            f4v st;
            #pragma unroll
            for(int v = 0; v < 4; v++) st[v] = acc[j][v];
            *(f4v*)&part[(((size_t)(ks * 2 + which) * 4096) + token) * 32 + es * 4] = st;
        }
    }
}

// ---------------- combine partials + sigmoid + top-2; which=0 also accumulates cntv
__global__ __launch_bounds__(256) void k_rfinal(const float* part, float* wvp, float* wop, int* cntv){
    int which = blockIdx.y;
    float* wout = which ? wop : wvp;
    __shared__ int cnt[32];
    int tid = threadIdx.x;
    if(tid < 32) cnt[tid] = 0;
    __syncthreads();
    int tok = blockIdx.x * 32 + (tid >> 3), h = tid & 7;
    f4v sum = {0.f, 0.f, 0.f, 0.f};
    #pragma unroll
    for(int s = 0; s < 8; s++)
        sum += *(const f4v*)&part[(((size_t)(s * 2 + which) * 4096) + tok) * 32 + h * 4];
    float g[4];
    #pragma unroll
    for(int e = 0; e < 4; e++) g[e] = 1.0f / (1.0f + expf(-sum[e]));
    f4v out;
    #pragma unroll
    for(int e = 0; e < 4; e++){
        int rank = 0;
        #pragma unroll
        for(int j = 0; j < 4; j++)
            rank += (g[j] > g[e]) || (g[j] == g[e] && j < e);
        out[e] = (rank < 2) ? g[e] : 0.0f;
        if(which == 0 && out[e] > 0.f) atomicAdd(&cnt[h * 4 + e], 1);
    }
    *(f4v*)&wout[(size_t)tok * 32 + h * 4] = out;
    __syncthreads();
    if(which == 0 && tid < 32 && cnt[tid]) atomicAdd(&cntv[tid], cnt[tid]);
}

// ---------------- gather with local scan: compact selected tokens per (h,e), write descv
__global__ __launch_bounds__(256) void k_gather(const float* wv, const int* cntv,
                                                int* idxv, float* gbufv, int* rpos, int* descv){
    int he = blockIdx.x, h = he >> 2, e = he & 3;
    int tid = threadIdx.x, lane = tid & 63, w = tid >> 6;
    __shared__ int ntl[33];
    if(tid == 0){
        int run = 0;
        #pragma unroll
        for(int j = 0; j < 32; j++){ ntl[j] = run; run += (cntv[j] + 127) >> 7; }
        ntl[32] = run;
    }
    __syncthreads();
    int base = ntl[he] << 7;
    for(int i = ntl[he] + tid; i < ntl[he + 1]; i += 256) descv[i] = he;
    if(he == 0)
        for(int i = ntl[32] + tid; i < 544; i += 256) descv[i] = -1;
    __shared__ int wsum[4];
    __shared__ int running;
    if(tid == 0) running = 0;
    __syncthreads();
    #pragma unroll 1
    for(int p = 0; p < 16; p++){
        int t = p * 256 + tid;
        float g = wv[(size_t)t * 32 + he];
        bool sel = g > 0.f;
        unsigned long long m = __ballot(sel);
        int lpref = __popcll(m & ((1ull << lane) - 1ull));
        if(lane == 0) wsum[w] = __popcll(m);
        __syncthreads();
        int rb = running;
        int woff = 0;
        #pragma unroll
        for(int j = 0; j < 4; j++) woff += (j < w) ? wsum[j] : 0;
        if(sel){
            int pos = base + rb + woff + lpref;
            idxv[pos] = t;
            gbufv[pos] = g;
            int slot = 0;
            #pragma unroll
            for(int j = 0; j < 4; j++)
                slot += (j < e && wv[(size_t)t * 32 + h * 4 + j] > 0.f) ? 1 : 0;
            rpos[(size_t)t * 16 + h * 2 + slot] = pos;
        }
        __syncthreads();
        if(tid == 0) running += wsum[0] + wsum[1] + wsum[2] + wsum[3];
        __syncthreads();
    }
    int tot = running;
    int aligned = (tot + 127) & ~127;
    for(int i = tid; i < aligned - tot; i += 256){
        idxv[base + tot + i] = 0;
        gbufv[base + tot + i] = 0.f;
    }
}

// ---------------- fused QK-projection + grouped V gather-GEMM: grid 1056
// BK=32 double-buffered 32.8KB LDS -> 4 blocks/CU (1024 slots); gathered tiles in natural
// order so the empty padding tiles (descv=-1) land at the END of the dispatch = no-op tail
__global__ __launch_bounds__(256) void k_gemmqkg(const short* qsb, const short* ksb,
                                                 const short* wqb, const short* wkb,
                                                 short* qo, short* ko, float scale,
                                                 const short* vsb, const short* wvt,
                                                 const int* descv, const int* idxv,
                                                 const float* gbufv, short* Cg){
    __shared__ __align__(16) short la[2][4096];
    __shared__ __align__(16) short lb[2][4096];
    __shared__ int lidx[128];
    int bid = blockIdx.x;
    int tid = threadIdx.x, lane = tid & 63, w = tid >> 6;
    int wm = (w >> 1) << 6, wn = (w & 1) << 6;
    int qr = lane & 15, grp = lane >> 4;
    int sr = lane >> 2, sc = lane & 3;      // staging: row-in-region, 16B chunk
    if(bid < 512){
        int wg = (bid & 7) * 64 + (bid >> 3);
        int which = wg >> 8, tl = wg & 255;
        int mt = tl >> 3, nt = tl & 7;
        const short* A = (which ? ksb : qsb) + ((size_t)(mt << 7)) * 1024;
        const short* B = (which ? wkb : wqb) + ((size_t)(nt << 7)) * 1024;
        short* out = which ? ko : qo;
        f4v acc[4][4];
        #pragma unroll
        for(int m = 0; m < 4; m++)
            #pragma unroll
            for(int n = 0; n < 4; n++) acc[m][n] = f4v{0.f, 0.f, 0.f, 0.f};
        #pragma unroll 1
        for(int t = -1; t < 32; t++){
            int nxt = t + 1;
            if(nxt < 32){
                int buf = nxt & 1, k0 = nxt << 5;
                #pragma unroll
                for(int p = 0; p < 2; p++){
                    int row = (p << 6) + (w << 4) + sr;
                    int gcol = (sc ^ ((row >> 1) & 3)) << 3;
                    int lo = ((p << 2) + w) << 9;
                    gload16(&A[(size_t)row * 1024 + k0 + gcol], &la[buf][lo]);
                    gload16(&B[(size_t)row * 1024 + k0 + gcol], &lb[buf][lo]);
                }
            }
            if(t >= 0){
                int cur = t & 1;
                s8v af[4], bf[4];
                #pragma unroll
                for(int m = 0; m < 4; m++){
                    int R = wm + m * 16 + qr;
                    af[m] = *(const s8v*)&la[cur][(R << 5) + ((grp ^ ((R >> 1) & 3)) << 3)];
                }
                #pragma unroll
                for(int n = 0; n < 4; n++){
                    int R = wn + n * 16 + qr;
                    bf[n] = *(const s8v*)&lb[cur][(R << 5) + ((grp ^ ((R >> 1) & 3)) << 3)];
                }
                #pragma unroll
                for(int m = 0; m < 4; m++)
                    #pragma unroll
                    for(int n = 0; n < 4; n++)
                        acc[m][n] = __builtin_amdgcn_mfma_f32_16x16x32_bf16(af[m], bf[n], acc[m][n], 0, 0, 0);
            }
            __syncthreads();
        }
        #pragma unroll
        for(int m = 0; m < 4; m++){
            int rb = (mt << 7) + wm + m * 16 + (grp << 2);
            #pragma unroll
            for(int n = 0; n < 4; n++){
                int col = (nt << 7) + wn + n * 16 + qr;
                #pragma unroll
                for(int r = 0; r < 4; r++)
                    out[(size_t)(rb + r) * 1024 + col] = (short)f2b(acc[m][n][r] * scale);
            }
        }
    } else {
        int gb = bid - 512;                  // natural order: empty tiles at grid tail
        int he = descv[gb];
        if(he < 0) return;
        int row0 = gb << 7;
        if(tid < 128) lidx[tid] = idxv[row0 + tid];
        __syncthreads();
        int arow[2];
        arow[0] = lidx[(w << 4) + sr];
        arow[1] = lidx[64 + (w << 4) + sr];
        const short* Bb = wvt + ((size_t)he << 17);
        f4v acc[4][4];
        #pragma unroll
        for(int m = 0; m < 4; m++)
            #pragma unroll
            for(int n = 0; n < 4; n++) acc[m][n] = f4v{0.f, 0.f, 0.f, 0.f};
        #pragma unroll 1
        for(int t = -1; t < 32; t++){
            int nxt = t + 1;
            if(nxt < 32){
                int buf = nxt & 1, k0 = nxt << 5;
                #pragma unroll
                for(int p = 0; p < 2; p++){
                    int row = (p << 6) + (w << 4) + sr;
                    int gcol = (sc ^ ((row >> 1) & 3)) << 3;
                    int lo = ((p << 2) + w) << 9;
                    gload16(&vsb[(size_t)arow[p] * 1024 + k0 + gcol], &la[buf][lo]);
                    gload16(&Bb[(size_t)row * 1024 + k0 + gcol], &lb[buf][lo]);
                }
            }
            if(t >= 0){
                int cur = t & 1;
                s8v af[4], bf[4];
                #pragma unroll
                for(int m = 0; m < 4; m++){
                    int R = wm + m * 16 + qr;
                    af[m] = *(const s8v*)&la[cur][(R << 5) + ((grp ^ ((R >> 1) & 3)) << 3)];
                }
                #pragma unroll
                for(int n = 0; n < 4; n++){
                    int R = wn + n * 16 + qr;
                    bf[n] = *(const s8v*)&lb[cur][(R << 5) + ((grp ^ ((R >> 1) & 3)) << 3)];
                }
                #pragma unroll
                for(int m = 0; m < 4; m++)
                    #pragma unroll
                    for(int n = 0; n < 4; n++)
                        acc[m][n] = __builtin_amdgcn_mfma_f32_16x16x32_bf16(af[m], bf[n], acc[m][n], 0, 0, 0);
            }
            __syncthreads();
        }
        #pragma unroll
        for(int m = 0; m < 4; m++){
            int rl = wm + m * 16 + (grp << 2);
            #pragma unroll
            for(int r = 0; r < 4; r++){
                float g = gbufv[row0 + rl + r];
                #pragma unroll
                for(int n = 0; n < 4; n++){
                    int col = wn + n * 16 + qr;
                    Cg[(size_t)(row0 + rl + r) * 128 + col] = (short)f2b(acc[m][n][r] * g);
                }
            }
        }
    }
}

// combine 2 gated expert rows per (token,h) + transpose into vt [bh][c][s]
__global__ __launch_bounds__(256) void k_vcomb(const short* Cg, const int* rpos, short* vtg){
    int bh = blockIdx.y, b = bh >> 3, h = bh & 7;
    int s0 = blockIdx.x * 32;
    __shared__ __align__(16) short t0[32][136];
    __shared__ __align__(16) short t1[32][136];
    __shared__ int rl[32][2];
    int tid = threadIdx.x;
    if(tid < 64){
        int i = tid >> 1, s = tid & 1;
        rl[i][s] = rpos[(size_t)(b * 1024 + s0 + i) * 16 + h * 2 + s];
    }
    __syncthreads();
    #pragma unroll
    for(int p = 0; p < 4; p++){
        int ch = tid + p * 256;
        int i = ch >> 5, slot = (ch >> 4) & 1, c8 = (ch & 15) << 3;
        s8v v = *(const s8v*)&Cg[(size_t)rl[i][slot] * 128 + c8];
        if(slot) *(s8v*)&t1[i][c8] = v;
        else     *(s8v*)&t0[i][c8] = v;
    }
    __syncthreads();
    #pragma unroll
    for(int p = 0; p < 16; p++){
        int idx = tid + p * 256;
        int s = idx & 31, c = idx >> 5;
        float v = b2f(t0[s][c]) + b2f(t1[s][c]);
        vtg[((size_t)bh * 128 + c) * 1024 + s0 + s] = (short)f2b(v);
    }
}

// ---------------- O projection: grid 512 = (tile, K-half)
// ksp==0 stores directly to d_out; ksp==1 stores po1 partial (k_red adds in place)
__global__ __launch_bounds__(256) void k_gemmo(const short* resw, const short* wot,
                                               float* out, float* po1){
    __shared__ __align__(16) short la[2][8192];
    __shared__ __align__(16) short lb[2][8192];
    int wg = (blockIdx.x & 7) * 64 + (blockIdx.x >> 3);
    int ksp = wg & 1, tile = wg >> 1;
    int mt = tile >> 3, nt = tile & 7;
    const short* A = resw + (size_t)(mt << 7) * 4096 + ksp * 2048;
    const short* B = wot + (size_t)(nt << 7) * 4096 + ksp * 2048;
    int tid = threadIdx.x, lane = tid & 63, w = tid >> 6;
    int wm = (w >> 1) << 6, wn = (w & 1) << 6;
    int qr = lane & 15, grp = lane >> 4;
    f4v acc[4][4];
    #pragma unroll
    for(int m = 0; m < 4; m++)
        #pragma unroll
        for(int n = 0; n < 4; n++) acc[m][n] = f4v{0.f, 0.f, 0.f, 0.f};
    #pragma unroll 1
    for(int t = -1; t < 32; t++){
        int nxt = t + 1;
        if(nxt < 32)
            stage2(A, B, 4096, 4096, nxt << 6, nxt << 6, la[nxt & 1], lb[nxt & 1], w, lane);
        if(t >= 0)
            mfma_block(la[t & 1], lb[t & 1], wm, wn, qr, grp, acc);
        __syncthreads();
    }
    float* dst = ksp ? po1 : out;
    #pragma unroll
    for(int m = 0; m < 4; m++){
        int rb = (mt << 7) + wm + m * 16 + (grp << 2);
        #pragma unroll
        for(int n = 0; n < 4; n++){
            int col = (nt << 7) + wn + n * 16 + qr;
            #pragma unroll
            for(int r = 0; r < 4; r++)
                dst[(size_t)(rb + r) * 1024 + col] = acc[m][n][r];
        }
    }
}

// ---------------- in-place accumulate: out += po1 (fp32), 8 floats/thread, grid 2048
__global__ __launch_bounds__(256) void k_red(float* out, const float* p1){
    size_t idx = ((size_t)blockIdx.x * 256 + threadIdx.x) * 8;
    f4v a0 = *(const f4v*)&out[idx],     b0 = *(const f4v*)&p1[idx];
    f4v a1 = *(const f4v*)&out[idx + 4], b1 = *(const f4v*)&p1[idx + 4];
    *(f4v*)&out[idx]     = a0 + b0;
    *(f4v*)&out[idx + 4] = a1 + b1;
}

// ---------------- flash attention: 4 waves x 16 q-rows, q-tile 64, flat grid 512, XCD swizzle
// lazy max-check, deferred per-lane l reduction, pl pitch 76 (conflict-reduced)
__global__ __launch_bounds__(256) void k_attn(const short* qg, const short* kg,
                                              const short* vtg, const float* wo, short* resw){
    __shared__ __align__(16) short lk[2][8192];
    __shared__ __align__(16) short lv[2][8192];
    __shared__ __align__(16) short pl[4][16 * 76];
    int swz = ((int)blockIdx.x & 7) * 64 + ((int)blockIdx.x >> 3);
    int bh = swz >> 4, qt = swz & 15;
    int b = bh >> 3, h = bh & 7;
    int w = threadIdx.x >> 6, lane = threadIdx.x & 63;
    int qr = lane & 15, grp = lane >> 4;
    int q0 = qt * 64 + w * 16;
    const short* vtb = vtg + ((size_t)bh << 17);
    short* pw = &pl[w][0];

    int tok = b * 1024 + q0 + qr;
    s8v qf[4];
    #pragma unroll
    for(int ks = 0; ks < 4; ks++)
        qf[ks] = *(const s8v*)&qg[(size_t)tok * 1024 + h * 128 + ks * 32 + grp * 8];
    f4v o[8];
    #pragma unroll
    for(int ct = 0; ct < 8; ct++) o[ct] = f4v{0.f, 0.f, 0.f, 0.f};
    float m_cur = -1e30f, l_lane = 0.f;

    int klr = lane >> 4, klc = lane & 15;
    int vlr = lane >> 3, vlc = lane & 7;

    #pragma unroll 1
    for(int t = -1; t < 16; t++){
        int nxt = t + 1;
        if(nxt < 16){
            int buf = nxt & 1, kv0 = nxt << 6;
            #pragma unroll
            for(int i = 0; i < 4; i++){
                int seg = (w << 2) + i;
                int kr = (seg << 2) + klr;
                int kc = klc ^ (kr & 7);
                gload16(&kg[(size_t)(b * 1024 + kv0 + kr) * 1024 + h * 128 + kc * 8], &lk[buf][seg << 9]);
                int vr = (seg << 3) + vlr;
                int vc = vlc ^ (vr & 7);
                gload16(&vtb[(size_t)vr * 1024 + kv0 + vc * 8], &lv[buf][seg << 9]);
            }
        }
        if(t >= 0){
            int cur = t & 1;
            f4v s[4];
            #pragma unroll
            for(int kt = 0; kt < 4; kt++) s[kt] = f4v{0.f, 0.f, 0.f, 0.f};
            __builtin_amdgcn_s_setprio(1);
            #pragma unroll
            for(int ks = 0; ks < 4; ks++){
                #pragma unroll
                for(int kt = 0; kt < 4; kt++){
                    int row = kt * 16 + qr;
                    s8v kf = *(const s8v*)&lk[cur][row * 128 + ((((ks << 2) + grp) ^ (row & 7)) << 3)];
                    s[kt] = __builtin_amdgcn_mfma_f32_16x16x32_bf16(kf, qf[ks], s[kt], 0, 0, 0);
                }
            }
            __builtin_amdgcn_s_setprio(0);
            // scores pre-scaled by log2e -> raw v_exp_f32 (2^x)
            float pm = s[0][0];
            #pragma unroll
            for(int kt = 0; kt < 4; kt++)
                #pragma unroll
                for(int r = 0; r < 4; r++) pm = fmaxf(pm, s[kt][r]);
            // lazy max-check: per-lane pm; "all lanes within THR" == "all row-maxes within THR"
            if(!__all(pm - m_cur <= 11.541f)){
                pm = fmaxf(pm, __shfl_xor(pm, 16));
                pm = fmaxf(pm, __shfl_xor(pm, 32));
                float mn = fmaxf(m_cur, pm);
                float fs = exp2v(m_cur - mn);
                #pragma unroll
                for(int ct = 0; ct < 8; ct++){
                    o[ct][0] *= fs; o[ct][1] *= fs; o[ct][2] *= fs; o[ct][3] *= fs;
                }
                l_lane *= fs;
                m_cur = mn;
            }
            // per-lane partial l (reduced once at epilogue; m-history is wave-common)
            #pragma unroll
            for(int kt = 0; kt < 4; kt++)
                #pragma unroll
                for(int r = 0; r < 4; r++){
                    s[kt][r] = exp2v(s[kt][r] - m_cur);
                    l_lane += s[kt][r];
                }
            #pragma unroll
            for(int kt = 0; kt < 4; kt++){
                uint2 pv;
                pv.x = cvtpk(s[kt][0], s[kt][1]);
                pv.y = cvtpk(s[kt][2], s[kt][3]);
                *(uint2*)&pw[qr * 76 + kt * 16 + grp * 4] = pv;
            }
            s8v pf0 = *(const s8v*)&pw[qr * 76 + grp * 8];
            s8v pf1 = *(const s8v*)&pw[qr * 76 + 32 + grp * 8];
            __builtin_amdgcn_s_setprio(1);
            #pragma unroll
            for(int ct = 0; ct < 8; ct++){
                int row = ct * 16 + qr;
                s8v vf0 = *(const s8v*)&lv[cur][row * 64 + ((grp ^ (row & 7)) << 3)];
                s8v vf1 = *(const s8v*)&lv[cur][row * 64 + (((4 + grp) ^ (row & 7)) << 3)];
                o[ct] = __builtin_amdgcn_mfma_f32_16x16x32_bf16(vf0, pf0, o[ct], 0, 0, 0);
                o[ct] = __builtin_amdgcn_mfma_f32_16x16x32_bf16(vf1, pf1, o[ct], 0, 0, 0);
            }
            __builtin_amdgcn_s_setprio(0);
        }
        __syncthreads();
    }
    // epilogue: reduce l across the 4 lane-groups, then write 4 gated expert strips
    l_lane += __shfl_xor(l_lane, 16);
    l_lane += __shfl_xor(l_lane, 32);
    float inv = 1.0f / l_lane;
    float g4[4];
    #pragma unroll
    for(int e = 0; e < 4; e++) g4[e] = wo[(size_t)tok * 32 + h * 4 + e];
    #pragma unroll
    for(int ct = 0; ct < 8; ct++){
        float v0 = o[ct][0] * inv, v1 = o[ct][1] * inv;
        float v2 = o[ct][2] * inv, v3 = o[ct][3] * inv;
        #pragma unroll
        for(int e = 0; e < 4; e++){
            uint2 sv;
            sv.x = cvtpk(v0 * g4[e], v1 * g4[e]);
            sv.y = cvtpk(v2 * g4[e], v3 * g4[e]);
            *(uint2*)&resw[(size_t)tok * 4096 + (h * 4 + e) * 128 + ct * 16 + grp * 4] = sv;
        }
    }
}

extern "C" void kernel_launch(void* const* d_in, const int* in_sizes, int n_in,
                              void* d_out, int out_size, void* d_ws, size_t ws_size,
                              hipStream_t stream){
    const float* q_src = (const float*)d_in[0];
    const float* k_src = (const float*)d_in[1];
    const float* v_src = (const float*)d_in[2];
    const float* Wq    = (const float*)d_in[3];
    const float* Wk    = (const float*)d_in[4];
    const float* Wv    = (const float*)d_in[5];
    const float* Wo    = (const float*)d_in[6];
    const float* selv  = (const float*)d_in[7];
    const float* selo  = (const float*)d_in[8];

    const size_t MB = 1ull << 20;
    char* ws = (char*)d_ws;
    short* qsb  = (short*)(ws + 0 * MB);    // [4096][1024] bf16  8MB
    short* ksb  = (short*)(ws + 8 * MB);    // 8MB
    short* vsb  = (short*)(ws + 16 * MB);   // 8MB (live until gemmqkg)
    short* wqb  = (short*)(ws + 24 * MB);   // 2MB
    short* wkb  = (short*)(ws + 26 * MB);   // 2MB
    short* wvt  = (short*)(ws + 28 * MB);   // [(he,c)=4096][1024] 8MB (live until gemmqkg)
    short* wot  = (short*)(ws + 36 * MB);   // [1024][4096] 8MB (live until gemmo)
    short* q    = (short*)(ws + 44 * MB);   // [4096 tok][1024] 8MB
    short* k    = (short*)(ws + 52 * MB);   // 8MB
    short* vt   = (short*)(ws + 60 * MB);   // [32bh][128][1024] 8MB
    float* wv   = (float*)(ws + 76 * MB);   // [4096][32] 512KB
    float* wo   = (float*)(ws + 76 * MB + 524288);
    float* part = (float*)(ws + 80 * MB);   // [8][2][4096][32] 8.4MB (dead after rfinal)
    short* Cg   = (short*)(ws + 80 * MB);   // [69632][128] bf16 17.8MB (dead after vcomb)
    int*   cntv = (int*)  (ws + 100 * MB);  // [32]
    int*   descv= (int*)  (ws + 100 * MB + 8192);   // [544]
    int*   idxv = (int*)  (ws + 101 * MB);  // [69632] 278KB
    float* gbufv= (float*)(ws + 102 * MB);  // [69632] 278KB
    int*   rposv= (int*)  (ws + 103 * MB);  // [4096][8][2] 512KB
    short* resw = (short*)(ws + 0 * MB);    // [4096][4096] 32MB (qsb..wvt dead at attn time)
    float* po1  = (float*)(ws + 80 * MB);   // [4096][1024] fp32 16MB (Cg/meta dead)

    // 128^-0.25 (applied to both q and k) x sqrt(log2e) so scores arrive in log2 units
    const float qk_scale = 0.29730177875068026f * 1.2011224087864498f;

    k_prep<<<dim3(15872), 256, 0, stream>>>(q_src, k_src, v_src, Wq, Wk, Wv, Wo, selv, selo,
                                            qsb, ksb, vsb, wqb, wkb, wvt, wot, part, cntv);
    k_rfinal<<<dim3(128, 2), 256, 0, stream>>>(part, wv, wo, cntv);
    k_gather<<<dim3(32), 256, 0, stream>>>(wv, cntv, idxv, gbufv, rposv, descv);
    k_gemmqkg<<<dim3(1056), 256, 0, stream>>>(qsb, ksb, wqb, wkb, q, k, qk_scale,
                                              vsb, wvt, descv, idxv, gbufv, Cg);
    k_vcomb<<<dim3(32, 32), 256, 0, stream>>>(Cg, rposv, vt);
    k_attn<<<dim3(512), 256, 0, stream>>>(q, k, vt, wo, resw);
    k_gemmo<<<dim3(512), 256, 0, stream>>>(resw, wot, (float*)d_out, po1);
    k_red<<<dim3(2048), 256, 0, stream>>>((float*)d_out, po1);
}

// Round 21
// 214.424 us; speedup vs baseline: 1.0109x; 1.0109x over previous
//
#include <hip/hip_runtime.h>

#define DEV __device__ __forceinline__

typedef __attribute__((ext_vector_type(8))) short s8v;
typedef __attribute__((ext_vector_type(4))) short s4v;
typedef __attribute__((ext_vector_type(4))) float f4v;

DEV unsigned short f2b(float f){
    unsigned u = __float_as_uint(f);
    u = (u + 0x7FFFu + ((u >> 16) & 1u)) >> 16;
    return (unsigned short)u;
}
DEV float b2f(short s){ return __uint_as_float(((unsigned)(unsigned short)s) << 16); }

DEV unsigned cvtpk(float lo, float hi){
    unsigned r;
    asm("v_cvt_pk_bf16_f32 %0, %1, %2" : "=v"(r) : "v"(lo), "v"(hi));
    return r;
}
DEV float exp2v(float x){
    float r;
    asm("v_exp_f32 %0, %1" : "=v"(r) : "v"(x));
    return r;
}

DEV void gload16(const void* g, void* l){
    __builtin_amdgcn_global_load_lds(
        (const __attribute__((address_space(1))) unsigned*)g,
        (__attribute__((address_space(3))) unsigned*)l, 16, 0, 0);
}

// B=4, S=1024, D=1024, H=8, E=4, K=2, DH=128

// ---- shared GEMM pieces: 128x128 tile, BK=64, XOR-swizzled LDS (used by gemmo) ----
DEV void stage2(const short* A, const short* B, int sA, int sB, int kA, int kB,
                short* la, short* lb, int w, int lane){
    int srow = lane >> 3;
    int swcol = ((lane & 7) ^ srow) << 3;
    #pragma unroll
    for(int it = 0; it < 4; it++){
        int seg = (w << 2) + it;
        int row = (seg << 3) + srow;
        gload16(&A[(size_t)row * sA + kA + swcol], &la[seg << 9]);
        gload16(&B[(size_t)row * sB + kB + swcol], &lb[seg << 9]);
    }
}

DEV void mfma_block(const short* la, const short* lb, int wm, int wn, int qr, int grp, f4v acc[4][4]){
    #pragma unroll
    for(int ks = 0; ks < 2; ks++){
        s8v af[4], bf[4];
        #pragma unroll
        for(int m = 0; m < 4; m++)
            af[m] = *(const s8v*)&la[(wm + m * 16 + qr) * 64 + ((((ks << 2) + grp) ^ (qr & 7)) << 3)];
        #pragma unroll
        for(int n = 0; n < 4; n++)
            bf[n] = *(const s8v*)&lb[(wn + n * 16 + qr) * 64 + ((((ks << 2) + grp) ^ (qr & 7)) << 3)];
        #pragma unroll
        for(int m = 0; m < 4; m++)
            #pragma unroll
            for(int n = 0; n < 4; n++)
                acc[m][n] = __builtin_amdgcn_mfma_f32_16x16x32_bf16(af[m], bf[n], acc[m][n], 0, 0, 0);
    }
}

// ---------------- prep mega-kernel: cvt (7168) + transposeWv (4096) + transposeWo (4096)
// + rlogits (512), flat block-id dispatch, grid 15872; block 0 also zeroes cntv
__global__ __launch_bounds__(256) void k_prep(const float* q_src, const float* k_src, const float* v_src,
                                              const float* Wq, const float* Wk, const float* Wv,
                                              const float* Wo, const float* selv, const float* selo,
                                              short* qsb, short* ksb, short* vsb, short* wqb, short* wkb,
                                              short* wvt, short* wot, float* part, int* cntv){
    __shared__ __align__(16) char smem[23040];
    int bid = blockIdx.x, tid = threadIdx.x;
    if(bid == 0 && tid < 32) cntv[tid] = 0;   // cntv consumed only by k_rfinal (after prep)
    if(bid < 7168){
        // ---- fp32 -> bf16 bulk convert
        int y, idx;
        if(bid < 6144){ y = bid >> 11; idx = (bid & 2047) * 256 + tid; }
        else { int i = bid - 6144; y = 3 + (i >> 9); idx = (i & 511) * 256 + tid; }
        const float* s = (y == 0) ? q_src : (y == 1) ? k_src : (y == 2) ? v_src : (y == 3) ? Wq : Wk;
        short* o = (y == 0) ? qsb : (y == 1) ? ksb : (y == 2) ? vsb : (y == 3) ? wqb : wkb;
        const float4* f = (const float4*)(s + (size_t)idx * 8);
        float4 a = f[0], b = f[1];
        s8v v;
        v[0] = f2b(a.x); v[1] = f2b(a.y); v[2] = f2b(a.z); v[3] = f2b(a.w);
        v[4] = f2b(b.x); v[5] = f2b(b.y); v[6] = f2b(b.z); v[7] = f2b(b.w);
        *(s8v*)(o + (size_t)idx * 8) = v;
    } else if(bid < 15360){
        // ---- transpose fp32 -> bf16
        const float* in; short* out; int R, C, c0, r0;
        if(bid < 11264){
            int i = bid - 7168;
            int z = i >> 7, rem = i & 127;
            R = 1024; C = 128;
            c0 = (rem & 3) * 32; r0 = (rem >> 2) * 32;
            in = Wv + (size_t)z * 131072;
            out = wvt + (size_t)z * 131072;
        } else {
            int i = bid - 11264;
            R = 4096; C = 1024;
            c0 = (i & 31) * 32; r0 = (i >> 5) * 32;
            in = Wo; out = wot;
        }
        float (*t)[33] = (float(*)[33])smem;
        int tx = tid & 31, ty = tid >> 5;
        #pragma unroll
        for(int p = 0; p < 4; p++){
            int r = p * 8 + ty;
            t[r][tx] = in[(size_t)(r0 + r) * C + c0 + tx];
        }
        __syncthreads();
        #pragma unroll
        for(int p = 0; p < 4; p++){
            int c = p * 8 + ty;
            out[(size_t)(c0 + c) * R + r0 + tx] = (short)f2b(t[tx][c]);
        }
    } else {
        // ---- routing logits: register-blocked fp32 GEMM, K-split x8
        int i = bid - 15360;
        int which = i & 1, bx = i >> 1;
        const float* src = which ? q_src : k_src;
        const float* sel = which ? selo : selv;
        int tt = bx >> 3, ks = bx & 7;
        int tok0 = tt << 7;
        float* lsrc = (float*)smem;              // [128][36]
        float* lsel = (float*)(smem + 18432);    // [32][36]
        int ts = tid & 31, es = tid >> 5;
        float acc[4][4];
        #pragma unroll
        for(int j = 0; j < 4; j++)
            #pragma unroll
            for(int q = 0; q < 4; q++) acc[j][q] = 0.f;
        #pragma unroll 1
        for(int c = 0; c < 4; c++){
            int k0 = (ks << 7) + (c << 5);
            {
                int row = tid >> 1, half = tid & 1;
                const float4* g = (const float4*)(src + (size_t)(tok0 + row) * 1024 + k0 + half * 16);
                #pragma unroll
                for(int qq = 0; qq < 4; qq++){
                    int qw = half * 4 + qq;
                    *(float4*)&lsrc[row * 36 + ((qw + row) & 7) * 4] = g[qq];
                }
            }
            {
                int row = tid >> 3, qw = tid & 7;
                *(float4*)&lsel[row * 36 + ((qw + row) & 7) * 4] =
                    *(const float4*)(sel + (size_t)row * 1024 + k0 + qw * 4);
            }
            __syncthreads();
            #pragma unroll
            for(int q = 0; q < 8; q++){
                float4 sv[4];
                #pragma unroll
                for(int v = 0; v < 4; v++){
                    int e = es * 4 + v;
                    sv[v] = *(const float4*)&lsel[e * 36 + ((q + e) & 7) * 4];
                }
                int slot = ((q + ts) & 7) * 4;
                #pragma unroll
                for(int j = 0; j < 4; j++){
                    float4 xv = *(const float4*)&lsrc[(ts + 32 * j) * 36 + slot];
                    #pragma unroll
                    for(int v = 0; v < 4; v++){
                        acc[j][v] = fmaf(xv.x, sv[v].x, acc[j][v]);
                        acc[j][v] = fmaf(xv.y, sv[v].y, acc[j][v]);
                        acc[j][v] = fmaf(xv.z, sv[v].z, acc[j][v]);
                        acc[j][v] = fmaf(xv.w, sv[v].w, acc[j][v]);
                    }
                }
            }
            __syncthreads();
        }
        #pragma unroll
        for(int j = 0; j < 4; j++){
            int token = tok0 + ts + 32 * j;
            f4v st;
            #pragma unroll
            for(int v = 0; v < 4; v++) st[v] = acc[j][v];
            *(f4v*)&part[(((size_t)(ks * 2 + which) * 4096) + token) * 32 + es * 4] = st;
        }
    }
}

// ---------------- combine partials + sigmoid + top-2; which=0 also accumulates cntv
__global__ __launch_bounds__(256) void k_rfinal(const float* part, float* wvp, float* wop, int* cntv){
    int which = blockIdx.y;
    float* wout = which ? wop : wvp;
    __shared__ int cnt[32];
    int tid = threadIdx.x;
    if(tid < 32) cnt[tid] = 0;
    __syncthreads();
    int tok = blockIdx.x * 32 + (tid >> 3), h = tid & 7;
    f4v sum = {0.f, 0.f, 0.f, 0.f};
    #pragma unroll
    for(int s = 0; s < 8; s++)
        sum += *(const f4v*)&part[(((size_t)(s * 2 + which) * 4096) + tok) * 32 + h * 4];
    float g[4];
    #pragma unroll
    for(int e = 0; e < 4; e++) g[e] = 1.0f / (1.0f + expf(-sum[e]));
    f4v out;
    #pragma unroll
    for(int e = 0; e < 4; e++){
        int rank = 0;
        #pragma unroll
        for(int j = 0; j < 4; j++)
            rank += (g[j] > g[e]) || (g[j] == g[e] && j < e);
        out[e] = (rank < 2) ? g[e] : 0.0f;
        if(which == 0 && out[e] > 0.f) atomicAdd(&cnt[h * 4 + e], 1);
    }
    *(f4v*)&wout[(size_t)tok * 32 + h * 4] = out;
    __syncthreads();
    if(which == 0 && tid < 32 && cnt[tid]) atomicAdd(&cntv[tid], cnt[tid]);
}

// ---------------- gather with local scan: compact selected tokens per (h,e), write descv
__global__ __launch_bounds__(256) void k_gather(const float* wv, const int* cntv,
                                                int* idxv, float* gbufv, int* rpos, int* descv){
    int he = blockIdx.x, h = he >> 2, e = he & 3;
    int tid = threadIdx.x, lane = tid & 63, w = tid >> 6;
    __shared__ int ntl[33];
    if(tid == 0){
        int run = 0;
        #pragma unroll
        for(int j = 0; j < 32; j++){ ntl[j] = run; run += (cntv[j] + 127) >> 7; }
        ntl[32] = run;
    }
    __syncthreads();
    int base = ntl[he] << 7;
    for(int i = ntl[he] + tid; i < ntl[he + 1]; i += 256) descv[i] = he;
    if(he == 0)
        for(int i = ntl[32] + tid; i < 544; i += 256) descv[i] = -1;
    __shared__ int wsum[4];
    __shared__ int running;
    if(tid == 0) running = 0;
    __syncthreads();
    #pragma unroll 1
    for(int p = 0; p < 16; p++){
        int t = p * 256 + tid;
        float g = wv[(size_t)t * 32 + he];
        bool sel = g > 0.f;
        unsigned long long m = __ballot(sel);
        int lpref = __popcll(m & ((1ull << lane) - 1ull));
        if(lane == 0) wsum[w] = __popcll(m);
        __syncthreads();
        int rb = running;
        int woff = 0;
        #pragma unroll
        for(int j = 0; j < 4; j++) woff += (j < w) ? wsum[j] : 0;
        if(sel){
            int pos = base + rb + woff + lpref;
            idxv[pos] = t;
            gbufv[pos] = g;
            int slot = 0;
            #pragma unroll
            for(int j = 0; j < 4; j++)
                slot += (j < e && wv[(size_t)t * 32 + h * 4 + j] > 0.f) ? 1 : 0;
            rpos[(size_t)t * 16 + h * 2 + slot] = pos;
        }
        __syncthreads();
        if(tid == 0) running += wsum[0] + wsum[1] + wsum[2] + wsum[3];
        __syncthreads();
    }
    int tot = running;
    int aligned = (tot + 127) & ~127;
    for(int i = tid; i < aligned - tot; i += 256){
        idxv[base + tot + i] = 0;
        gbufv[base + tot + i] = 0.f;
    }
}

// ---------------- fused QK-projection + grouped V gather-GEMM: grid 1056
// BK=32 double-buffered 32.8KB LDS -> 4 blocks/CU; XCD swizzle on both halves
__global__ __launch_bounds__(256) void k_gemmqkg(const short* qsb, const short* ksb,
                                                 const short* wqb, const short* wkb,
                                                 short* qo, short* ko, float scale,
                                                 const short* vsb, const short* wvt,
                                                 const int* descv, const int* idxv,
                                                 const float* gbufv, short* Cg){
    __shared__ __align__(16) short la[2][4096];
    __shared__ __align__(16) short lb[2][4096];
    __shared__ int lidx[128];
    int bid = blockIdx.x;
    int tid = threadIdx.x, lane = tid & 63, w = tid >> 6;
    int wm = (w >> 1) << 6, wn = (w & 1) << 6;
    int qr = lane & 15, grp = lane >> 4;
    int sr = lane >> 2, sc = lane & 3;      // staging: row-in-region, 16B chunk
    if(bid < 512){
        int wg = (bid & 7) * 64 + (bid >> 3);
        int which = wg >> 8, tl = wg & 255;
        int mt = tl >> 3, nt = tl & 7;
        const short* A = (which ? ksb : qsb) + ((size_t)(mt << 7)) * 1024;
        const short* B = (which ? wkb : wqb) + ((size_t)(nt << 7)) * 1024;
        short* out = which ? ko : qo;
        f4v acc[4][4];
        #pragma unroll
        for(int m = 0; m < 4; m++)
            #pragma unroll
            for(int n = 0; n < 4; n++) acc[m][n] = f4v{0.f, 0.f, 0.f, 0.f};
        #pragma unroll 1
        for(int t = -1; t < 32; t++){
            int nxt = t + 1;
            if(nxt < 32){
                int buf = nxt & 1, k0 = nxt << 5;
                #pragma unroll
                for(int p = 0; p < 2; p++){
                    int row = (p << 6) + (w << 4) + sr;
                    int gcol = (sc ^ ((row >> 1) & 3)) << 3;
                    int lo = ((p << 2) + w) << 9;
                    gload16(&A[(size_t)row * 1024 + k0 + gcol], &la[buf][lo]);
                    gload16(&B[(size_t)row * 1024 + k0 + gcol], &lb[buf][lo]);
                }
            }
            if(t >= 0){
                int cur = t & 1;
                s8v af[4], bf[4];
                #pragma unroll
                for(int m = 0; m < 4; m++){
                    int R = wm + m * 16 + qr;
                    af[m] = *(const s8v*)&la[cur][(R << 5) + ((grp ^ ((R >> 1) & 3)) << 3)];
                }
                #pragma unroll
                for(int n = 0; n < 4; n++){
                    int R = wn + n * 16 + qr;
                    bf[n] = *(const s8v*)&lb[cur][(R << 5) + ((grp ^ ((R >> 1) & 3)) << 3)];
                }
                #pragma unroll
                for(int m = 0; m < 4; m++)
                    #pragma unroll
                    for(int n = 0; n < 4; n++)
                        acc[m][n] = __builtin_amdgcn_mfma_f32_16x16x32_bf16(af[m], bf[n], acc[m][n], 0, 0, 0);
            }
            __syncthreads();
        }
        #pragma unroll
        for(int m = 0; m < 4; m++){
            int rb = (mt << 7) + wm + m * 16 + (grp << 2);
            #pragma unroll
            for(int n = 0; n < 4; n++){
                int col = (nt << 7) + wn + n * 16 + qr;
                #pragma unroll
                for(int r = 0; r < 4; r++)
                    out[(size_t)(rb + r) * 1024 + col] = (short)f2b(acc[m][n][r] * scale);
            }
        }
    } else {
        int gb0 = bid - 512;
        int gb = (gb0 & 7) * 68 + (gb0 >> 3);   // XCD swizzle: consecutive gb on one XCD
        int he = descv[gb];
        if(he < 0) return;
        int row0 = gb << 7;
        if(tid < 128) lidx[tid] = idxv[row0 + tid];
        __syncthreads();
        int arow[2];
        arow[0] = lidx[(w << 4) + sr];
        arow[1] = lidx[64 + (w << 4) + sr];
        const short* Bb = wvt + ((size_t)he << 17);
        f4v acc[4][4];
        #pragma unroll
        for(int m = 0; m < 4; m++)
            #pragma unroll
            for(int n = 0; n < 4; n++) acc[m][n] = f4v{0.f, 0.f, 0.f, 0.f};
        #pragma unroll 1
        for(int t = -1; t < 32; t++){
            int nxt = t + 1;
            if(nxt < 32){
                int buf = nxt & 1, k0 = nxt << 5;
                #pragma unroll
                for(int p = 0; p < 2; p++){
                    int row = (p << 6) + (w << 4) + sr;
                    int gcol = (sc ^ ((row >> 1) & 3)) << 3;
                    int lo = ((p << 2) + w) << 9;
                    gload16(&vsb[(size_t)arow[p] * 1024 + k0 + gcol], &la[buf][lo]);
                    gload16(&Bb[(size_t)row * 1024 + k0 + gcol], &lb[buf][lo]);
                }
            }
            if(t >= 0){
                int cur = t & 1;
                s8v af[4], bf[4];
                #pragma unroll
                for(int m = 0; m < 4; m++){
                    int R = wm + m * 16 + qr;
                    af[m] = *(const s8v*)&la[cur][(R << 5) + ((grp ^ ((R >> 1) & 3)) << 3)];
                }
                #pragma unroll
                for(int n = 0; n < 4; n++){
                    int R = wn + n * 16 + qr;
                    bf[n] = *(const s8v*)&lb[cur][(R << 5) + ((grp ^ ((R >> 1) & 3)) << 3)];
                }
                #pragma unroll
                for(int m = 0; m < 4; m++)
                    #pragma unroll
                    for(int n = 0; n < 4; n++)
                        acc[m][n] = __builtin_amdgcn_mfma_f32_16x16x32_bf16(af[m], bf[n], acc[m][n], 0, 0, 0);
            }
            __syncthreads();
        }
        #pragma unroll
        for(int m = 0; m < 4; m++){
            int rl = wm + m * 16 + (grp << 2);
            #pragma unroll
            for(int r = 0; r < 4; r++){
                float g = gbufv[row0 + rl + r];
                #pragma unroll
                for(int n = 0; n < 4; n++){
                    int col = wn + n * 16 + qr;
                    Cg[(size_t)(row0 + rl + r) * 128 + col] = (short)f2b(acc[m][n][r] * g);
                }
            }
        }
    }
}

// combine 2 gated expert rows per (token,h) + transpose into vt [bh][c][s]
__global__ __launch_bounds__(256) void k_vcomb(const short* Cg, const int* rpos, short* vtg){
    int bh = blockIdx.y, b = bh >> 3, h = bh & 7;
    int s0 = blockIdx.x * 32;
    __shared__ __align__(16) short t0[32][136];
    __shared__ __align__(16) short t1[32][136];
    __shared__ int rl[32][2];
    int tid = threadIdx.x;
    if(tid < 64){
        int i = tid >> 1, s = tid & 1;
        rl[i][s] = rpos[(size_t)(b * 1024 + s0 + i) * 16 + h * 2 + s];
    }
    __syncthreads();
    #pragma unroll
    for(int p = 0; p < 4; p++){
        int ch = tid + p * 256;
        int i = ch >> 5, slot = (ch >> 4) & 1, c8 = (ch & 15) << 3;
        s8v v = *(const s8v*)&Cg[(size_t)rl[i][slot] * 128 + c8];
        if(slot) *(s8v*)&t1[i][c8] = v;
        else     *(s8v*)&t0[i][c8] = v;
    }
    __syncthreads();
    #pragma unroll
    for(int p = 0; p < 16; p++){
        int idx = tid + p * 256;
        int s = idx & 31, c = idx >> 5;
        float v = b2f(t0[s][c]) + b2f(t1[s][c]);
        vtg[((size_t)bh * 128 + c) * 1024 + s0 + s] = (short)f2b(v);
    }
}

// ---------------- O projection: grid 512 = (tile, K-half)
// ksp==0 stores directly to d_out; ksp==1 stores po1 partial (k_red adds in place)
__global__ __launch_bounds__(256) void k_gemmo(const short* resw, const short* wot,
                                               float* out, float* po1){
    __shared__ __align__(16) short la[2][8192];
    __shared__ __align__(16) short lb[2][8192];
    int wg = (blockIdx.x & 7) * 64 + (blockIdx.x >> 3);
    int ksp = wg & 1, tile = wg >> 1;
    int mt = tile >> 3, nt = tile & 7;
    const short* A = resw + (size_t)(mt << 7) * 4096 + ksp * 2048;
    const short* B = wot + (size_t)(nt << 7) * 4096 + ksp * 2048;
    int tid = threadIdx.x, lane = tid & 63, w = tid >> 6;
    int wm = (w >> 1) << 6, wn = (w & 1) << 6;
    int qr = lane & 15, grp = lane >> 4;
    f4v acc[4][4];
    #pragma unroll
    for(int m = 0; m < 4; m++)
        #pragma unroll
        for(int n = 0; n < 4; n++) acc[m][n] = f4v{0.f, 0.f, 0.f, 0.f};
    #pragma unroll 1
    for(int t = -1; t < 32; t++){
        int nxt = t + 1;
        if(nxt < 32)
            stage2(A, B, 4096, 4096, nxt << 6, nxt << 6, la[nxt & 1], lb[nxt & 1], w, lane);
        if(t >= 0)
            mfma_block(la[t & 1], lb[t & 1], wm, wn, qr, grp, acc);
        __syncthreads();
    }
    float* dst = ksp ? po1 : out;
    #pragma unroll
    for(int m = 0; m < 4; m++){
        int rb = (mt << 7) + wm + m * 16 + (grp << 2);
        #pragma unroll
        for(int n = 0; n < 4; n++){
            int col = (nt << 7) + wn + n * 16 + qr;
            #pragma unroll
            for(int r = 0; r < 4; r++)
                dst[(size_t)(rb + r) * 1024 + col] = acc[m][n][r];
        }
    }
}

// ---------------- in-place accumulate: out += po1 (fp32), 8 floats/thread, grid 2048
__global__ __launch_bounds__(256) void k_red(float* out, const float* p1){
    size_t idx = ((size_t)blockIdx.x * 256 + threadIdx.x) * 8;
    f4v a0 = *(const f4v*)&out[idx],     b0 = *(const f4v*)&p1[idx];
    f4v a1 = *(const f4v*)&out[idx + 4], b1 = *(const f4v*)&p1[idx + 4];
    *(f4v*)&out[idx]     = a0 + b0;
    *(f4v*)&out[idx + 4] = a1 + b1;
}

// ---------------- flash attention: 4 waves x 16 q-rows, q-tile 64, flat grid 512, XCD swizzle
// lazy max-check, deferred per-lane l reduction, pl pitch 76 (conflict-reduced)
__global__ __launch_bounds__(256) void k_attn(const short* qg, const short* kg,
                                              const short* vtg, const float* wo, short* resw){
    __shared__ __align__(16) short lk[2][8192];
    __shared__ __align__(16) short lv[2][8192];
    __shared__ __align__(16) short pl[4][16 * 76];
    int swz = ((int)blockIdx.x & 7) * 64 + ((int)blockIdx.x >> 3);
    int bh = swz >> 4, qt = swz & 15;
    int b = bh >> 3, h = bh & 7;
    int w = threadIdx.x >> 6, lane = threadIdx.x & 63;
    int qr = lane & 15, grp = lane >> 4;
    int q0 = qt * 64 + w * 16;
    const short* vtb = vtg + ((size_t)bh << 17);
    short* pw = &pl[w][0];

    int tok = b * 1024 + q0 + qr;
    s8v qf[4];
    #pragma unroll
    for(int ks = 0; ks < 4; ks++)
        qf[ks] = *(const s8v*)&qg[(size_t)tok * 1024 + h * 128 + ks * 32 + grp * 8];
    f4v o[8];
    #pragma unroll
    for(int ct = 0; ct < 8; ct++) o[ct] = f4v{0.f, 0.f, 0.f, 0.f};
    float m_cur = -1e30f, l_lane = 0.f;

    int klr = lane >> 4, klc = lane & 15;
    int vlr = lane >> 3, vlc = lane & 7;

    #pragma unroll 1
    for(int t = -1; t < 16; t++){
        int nxt = t + 1;
        if(nxt < 16){
            int buf = nxt & 1, kv0 = nxt << 6;
            #pragma unroll
            for(int i = 0; i < 4; i++){
                int seg = (w << 2) + i;
                int kr = (seg << 2) + klr;
                int kc = klc ^ (kr & 7);
                gload16(&kg[(size_t)(b * 1024 + kv0 + kr) * 1024 + h * 128 + kc * 8], &lk[buf][seg << 9]);
                int vr = (seg << 3) + vlr;
                int vc = vlc ^ (vr & 7);
                gload16(&vtb[(size_t)vr * 1024 + kv0 + vc * 8], &lv[buf][seg << 9]);
            }
        }
        if(t >= 0){
            int cur = t & 1;
            f4v s[4];
            #pragma unroll
            for(int kt = 0; kt < 4; kt++) s[kt] = f4v{0.f, 0.f, 0.f, 0.f};
            __builtin_amdgcn_s_setprio(1);
            #pragma unroll
            for(int ks = 0; ks < 4; ks++){
                #pragma unroll
                for(int kt = 0; kt < 4; kt++){
                    int row = kt * 16 + qr;
                    s8v kf = *(const s8v*)&lk[cur][row * 128 + ((((ks << 2) + grp) ^ (row & 7)) << 3)];
                    s[kt] = __builtin_amdgcn_mfma_f32_16x16x32_bf16(kf, qf[ks], s[kt], 0, 0, 0);
                }
            }
            __builtin_amdgcn_s_setprio(0);
            // scores pre-scaled by log2e -> raw v_exp_f32 (2^x)
            float pm = s[0][0];
            #pragma unroll
            for(int kt = 0; kt < 4; kt++)
                #pragma unroll
                for(int r = 0; r < 4; r++) pm = fmaxf(pm, s[kt][r]);
            // lazy max-check: per-lane pm; "all lanes within THR" == "all row-maxes within THR"
            if(!__all(pm - m_cur <= 11.541f)){
                pm = fmaxf(pm, __shfl_xor(pm, 16));
                pm = fmaxf(pm, __shfl_xor(pm, 32));
                float mn = fmaxf(m_cur, pm);
                float fs = exp2v(m_cur - mn);
                #pragma unroll
                for(int ct = 0; ct < 8; ct++){
                    o[ct][0] *= fs; o[ct][1] *= fs; o[ct][2] *= fs; o[ct][3] *= fs;
                }
                l_lane *= fs;
                m_cur = mn;
            }
            // per-lane partial l (reduced once at epilogue; m-history is wave-common)
            #pragma unroll
            for(int kt = 0; kt < 4; kt++)
                #pragma unroll
                for(int r = 0; r < 4; r++){
                    s[kt][r] = exp2v(s[kt][r] - m_cur);
                    l_lane += s[kt][r];
                }
            #pragma unroll
            for(int kt = 0; kt < 4; kt++){
                uint2 pv;
                pv.x = cvtpk(s[kt][0], s[kt][1]);
                pv.y = cvtpk(s[kt][2], s[kt][3]);
                *(uint2*)&pw[qr * 76 + kt * 16 + grp * 4] = pv;
            }
            s8v pf0 = *(const s8v*)&pw[qr * 76 + grp * 8];
            s8v pf1 = *(const s8v*)&pw[qr * 76 + 32 + grp * 8];
            __builtin_amdgcn_s_setprio(1);
            #pragma unroll
            for(int ct = 0; ct < 8; ct++){
                int row = ct * 16 + qr;
                s8v vf0 = *(const s8v*)&lv[cur][row * 64 + ((grp ^ (row & 7)) << 3)];
                s8v vf1 = *(const s8v*)&lv[cur][row * 64 + (((4 + grp) ^ (row & 7)) << 3)];
                o[ct] = __builtin_amdgcn_mfma_f32_16x16x32_bf16(vf0, pf0, o[ct], 0, 0, 0);
                o[ct] = __builtin_amdgcn_mfma_f32_16x16x32_bf16(vf1, pf1, o[ct], 0, 0, 0);
            }
            __builtin_amdgcn_s_setprio(0);
        }
        __syncthreads();
    }
    // epilogue: reduce l across the 4 lane-groups, then write 4 gated expert strips
    l_lane += __shfl_xor(l_lane, 16);
    l_lane += __shfl_xor(l_lane, 32);
    float inv = 1.0f / l_lane;
    float g4[4];
    #pragma unroll
    for(int e = 0; e < 4; e++) g4[e] = wo[(size_t)tok * 32 + h * 4 + e];
    #pragma unroll
    for(int ct = 0; ct < 8; ct++){
        float v0 = o[ct][0] * inv, v1 = o[ct][1] * inv;
        float v2 = o[ct][2] * inv, v3 = o[ct][3] * inv;
        #pragma unroll
        for(int e = 0; e < 4; e++){
            uint2 sv;
            sv.x = cvtpk(v0 * g4[e], v1 * g4[e]);
            sv.y = cvtpk(v2 * g4[e], v3 * g4[e]);
            *(uint2*)&resw[(size_t)tok * 4096 + (h * 4 + e) * 128 + ct * 16 + grp * 4] = sv;
        }
    }
}

extern "C" void kernel_launch(void* const* d_in, const int* in_sizes, int n_in,
                              void* d_out, int out_size, void* d_ws, size_t ws_size,
                              hipStream_t stream){
    const float* q_src = (const float*)d_in[0];
    const float* k_src = (const float*)d_in[1];
    const float* v_src = (const float*)d_in[2];
    const float* Wq    = (const float*)d_in[3];
    const float* Wk    = (const float*)d_in[4];
    const float* Wv    = (const float*)d_in[5];
    const float* Wo    = (const float*)d_in[6];
    const float* selv  = (const float*)d_in[7];
    const float* selo  = (const float*)d_in[8];

    const size_t MB = 1ull << 20;
    char* ws = (char*)d_ws;
    short* qsb  = (short*)(ws + 0 * MB);    // [4096][1024] bf16  8MB
    short* ksb  = (short*)(ws + 8 * MB);    // 8MB
    short* vsb  = (short*)(ws + 16 * MB);   // 8MB (live until gemmqkg)
    short* wqb  = (short*)(ws + 24 * MB);   // 2MB
    short* wkb  = (short*)(ws + 26 * MB);   // 2MB
    short* wvt  = (short*)(ws + 28 * MB);   // [(he,c)=4096][1024] 8MB (live until gemmqkg)
    short* wot  = (short*)(ws + 36 * MB);   // [1024][4096] 8MB (live until gemmo)
    short* q    = (short*)(ws + 44 * MB);   // [4096 tok][1024] 8MB
    short* k    = (short*)(ws + 52 * MB);   // 8MB
    short* vt   = (short*)(ws + 60 * MB);   // [32bh][128][1024] 8MB
    float* wv   = (float*)(ws + 76 * MB);   // [4096][32] 512KB
    float* wo   = (float*)(ws + 76 * MB + 524288);
    float* part = (float*)(ws + 80 * MB);   // [8][2][4096][32] 8.4MB (dead after rfinal)
    short* Cg   = (short*)(ws + 80 * MB);   // [69632][128] bf16 17.8MB (dead after vcomb)
    int*   cntv = (int*)  (ws + 100 * MB);  // [32]
    int*   descv= (int*)  (ws + 100 * MB + 8192);   // [544]
    int*   idxv = (int*)  (ws + 101 * MB);  // [69632] 278KB
    float* gbufv= (float*)(ws + 102 * MB);  // [69632] 278KB
    int*   rposv= (int*)  (ws + 103 * MB);  // [4096][8][2] 512KB
    short* resw = (short*)(ws + 0 * MB);    // [4096][4096] 32MB (qsb..wvt dead at attn time)
    float* po1  = (float*)(ws + 80 * MB);   // [4096][1024] fp32 16MB (Cg/meta dead)

    // 128^-0.25 (applied to both q and k) x sqrt(log2e) so scores arrive in log2 units
    const float qk_scale = 0.29730177875068026f * 1.2011224087864498f;

    k_prep<<<dim3(15872), 256, 0, stream>>>(q_src, k_src, v_src, Wq, Wk, Wv, Wo, selv, selo,
                                            qsb, ksb, vsb, wqb, wkb, wvt, wot, part, cntv);
    k_rfinal<<<dim3(128, 2), 256, 0, stream>>>(part, wv, wo, cntv);
    k_gather<<<dim3(32), 256, 0, stream>>>(wv, cntv, idxv, gbufv, rposv, descv);
    k_gemmqkg<<<dim3(1056), 256, 0, stream>>>(qsb, ksb, wqb, wkb, q, k, qk_scale,
                                              vsb, wvt, descv, idxv, gbufv, Cg);
    k_vcomb<<<dim3(32, 32), 256, 0, stream>>>(Cg, rposv, vt);
    k_attn<<<dim3(512), 256, 0, stream>>>(q, k, vt, wo, resw);
    k_gemmo<<<dim3(512), 256, 0, stream>>>(resw, wot, (float*)d_out, po1);
    k_red<<<dim3(2048), 256, 0, stream>>>((float*)d_out, po1);
}